// Round 25
// baseline (5812.852 us; speedup 1.0000x reference)
//
#include <hip/hip_runtime.h>
#include <math.h>
#include <stdint.h>

namespace {

typedef __attribute__((ext_vector_type(8))) short short8v;   // 8 bf16 = 4 VGPR
typedef __attribute__((ext_vector_type(4))) float f32x4;

constexpr int TT = 256;

// ---- ws float offsets (total 12,959,744 floats = 51.84 MB) ----
constexpr size_t OFF_ST = 0;          // c0T,h1T,c1T [3][64][512]
constexpr size_t OFF_P0 = 98304;      // [2][64][6144]
constexpr size_t OFF_P1 = 884736;     // [2][64][6144]
constexpr size_t OFF_WF = 1671168;    // 20,447,232 ushorts: frag weights hi|lo
constexpr size_t OFF_FF = 11894784;   // 2,129,920 ushorts: frag features hi|lo
constexpr size_t WS_NEED = 12959744ull * 4;

constexpr size_t WFLO = 10223616;     // ushort offset of weight lo plane
constexpr size_t FFLO = 1064960;      // ushort offset of feature lo plane
constexpr size_t FLB1 = 409600;       // feature base of layer 1 (ushorts)

__device__ __forceinline__ float sigmoidf_(float v) { return 1.0f / (1.0f + expf(-v)); }

__device__ __forceinline__ ushort bf16h(float v) {          // RNE f32 -> bf16 bits
    uint32_t u = __float_as_uint(v);
    return (ushort)((u + 0x7fffu + ((u >> 16) & 1u)) >> 16);
}
__device__ __forceinline__ float bf16f(ushort h) { return __uint_as_float(((uint32_t)h) << 16); }

// Cox-de Boor, GRID_SIZE=5, ORDER=3 (verified rounds 7-24)
__device__ __forceinline__ void bspline8(float x, float* out) {
    const float KG[12] = {-2.2f,-1.8f,-1.4f,-1.0f,-0.6f,-0.2f,
                           0.2f, 0.6f, 1.0f, 1.4f, 1.8f, 2.2f};
    float b[11];
#pragma unroll
    for (int i = 0; i < 11; ++i)
        b[i] = (x >= KG[i] && x < KG[i + 1]) ? 1.0f : 0.0f;
#pragma unroll
    for (int p = 1; p <= 3; ++p) {
#pragma unroll
        for (int i = 0; i + p < 11; ++i) {
            float l = (x - KG[i])         * (1.0f / (KG[i + p] - KG[i]));
            float r = (KG[i + p + 1] - x) * (1.0f / (KG[i + p + 1] - KG[i + 1]));
            b[i] = l * b[i] + r * b[i + 1];
        }
    }
#pragma unroll
    for (int i = 0; i < 8; ++i) out[i] = b[i];
}

// Write z, silu, 8 bases in FRAGMENT order. lo-plane only for z and silu
// (spline branch runs plain-bf16: basis lo never read).
__device__ __forceinline__ void putFeat(int l, int k, int b, float z,
                                        ushort* __restrict__ fe)
{
    const int NSL = l ? 16 : 10, KC = l ? 512 : 320;
    const int kh = (k >= KC) ? 1 : 0, kr = k - kh * KC;
    const int sl = kr >> 5, kg = (kr >> 3) & 3, j = kr & 7;
    const size_t cell = (size_t)((b >> 4) * 64 + (b & 15) + 16 * kg) * 8 + j;
    const size_t LB = l ? FLB1 : 0;
    const size_t slb = ((size_t)kh * NSL + sl) * 2048 + cell;
    const size_t pstep = (size_t)2 * NSL * 2048;

    auto putp = [&](int p, float v, bool wl) {
        size_t idx = LB + (size_t)p * pstep + slb;
        ushort h = bf16h(v);
        fe[idx] = h;
        if (wl) fe[FFLO + idx] = bf16h(v - bf16f(h));
    };
    putp(0, z, true);
    putp(1, z / (1.0f + expf(-z)), true);
    float bs[8];
    bspline8(z, bs);
#pragma unroll
    for (int r = 0; r < 8; ++r) putp(2 + r, bs[r], false);
}

__global__ __launch_bounds__(256) void sentinel_kernel(float* out, float v) {
    int i = blockIdx.x * 256 + threadIdx.x;
    if (i < 8192) out[i] = v;
}

// Build fragment-ordered split weights (identical to rounds 19-24; spline lo
// still built but never read — harmless one-time setup).
__global__ __launch_bounds__(256) void wbuild_kernel(
    ushort* __restrict__ wf,
    const float* __restrict__ w_ih0, const float* __restrict__ w_hh0,
    const float* __restrict__ kb0, const float* __restrict__ ksp0,
    const float* __restrict__ w_ih1, const float* __restrict__ w_hh1,
    const float* __restrict__ kb1, const float* __restrict__ ksp1)
{
    const int gid = blockIdx.x * 256 + threadIdx.x;   // 4992*256 = 19968*64
    const int s = gid >> 6, lane = gid & 63;
    int wid, sl;
    if (s < 7680) { wid = s / 10; sl = s % 10; }
    else          { wid = 768 + (s - 7680) / 16; sl = (s - 7680) % 16; }
    const int l = wid >= 768 ? 1 : 0;
    const int r2 = wid - l * 768;
    const int kh = r2 >= 384 ? 1 : 0;
    const int tile = r2 - kh * 384;
    const int IN = l ? 512 : 128, W = IN + 512, KC = W >> 1;
    const int m = lane & 15, kg = lane >> 4;
    const int k0 = kh * KC + sl * 32;
    const int kk = k0 + kg * 8;
    const int o0 = tile * 16;

    const float* w_ih = l ? w_ih1 : w_ih0;
    const float* w_hh = l ? w_hh1 : w_hh0;
    const float* kb   = l ? kb1 : kb0;
    const float* ksp  = l ? ksp1 : ksp0;

    float vv[8];
    if (tile < 96) {
        const int row = o0 + m;
#pragma unroll
        for (int j = 0; j < 8; ++j) {
            const int k = kk + j;
            vv[j] = (k0 < IN) ? w_ih[(size_t)row * IN + k]
                              : w_hh[(size_t)row * 512 + (k - IN)];
        }
    } else if (tile < 128) {
        const int row = (tile - 96) * 16 + m;
#pragma unroll
        for (int j = 0; j < 8; ++j) vv[j] = kb[(size_t)row * W + kk + j];
    } else {
        const int rr = (tile - 128) >> 5, op = ((tile - 128) & 31) * 16 + m;
#pragma unroll
        for (int j = 0; j < 8; ++j)
            vv[j] = ksp[((size_t)op * W + kk + j) * 8 + rr];
    }
    const size_t base = (size_t)s * 512 + (size_t)lane * 8;
#pragma unroll
    for (int j = 0; j < 8; ++j) {
        ushort h = bf16h(vv[j]);
        wf[base + j] = h;
        wf[WFLO + base + j] = bf16h(vv[j] - bf16f(h));
    }
}

// states zero + t=0 x-features + zero-state hidden features for both layers
__global__ __launch_bounds__(256) void prologue_kernel(
    const float* __restrict__ x, float* __restrict__ ws)
{
    ushort* fe = (ushort*)(ws + OFF_FF);
    const int g = blockIdx.x * 256 + threadIdx.x;    // 672*256 = 172032
    if (g < 98304) {
        ws[OFF_ST + g] = 0.0f;                       // c0T,h1T,c1T
    } else if (g < 106496) {                         // t=0 x feats (k<128)
        const int i = g - 98304, k = i & 127, b = i >> 7;
        putFeat(0, k, b, x[((size_t)b * TT) * 128 + k], fe);
    } else if (g < 139264) {                         // L0 hidden feats h0(-1)=0
        const int i = g - 106496, o = i & 511, b = i >> 9;
        putFeat(0, 128 + o, b, 0.0f, fe);
    } else {                                         // L1 hidden feats h1(-1)=0
        const int i = g - 139264, o = i & 511, b = i >> 9;
        putFeat(1, 512 + o, b, 0.0f, fe);
    }
}

// phase A: MFMA GEMM, fragment-ordered memory, double-buffered LDS, XCD
// swizzle (all r23). ONE change: spline tiles (p>=2) run PLAIN BF16 —
// 1 MFMA (whi x bh), no weight-lo / basis-lo loads. Gates + base keep the
// full 3-product split-bf16. useLo is block-uniform (blocks are type-pure).
__global__ __launch_bounds__(256) void phaseA_kernel(
    float* __restrict__ ws, int s)
{
    __shared__ short8v sfh[2][256], sfl[2][256];     // 16 KB

    const int t = threadIdx.x, lane = t & 63;
    const int wv = __builtin_amdgcn_readfirstlane(t >> 6);
    const int bid = blockIdx.x;                      // 0..383
    const int task = ((bid & 7) * 48) + (bid >> 3);  // XCD-contiguous tasks
    const int l  = task >= 192 ? 1 : 0;
    if (l ? (s < 1) : (s >= TT)) return;             // block-uniform
    const int r3 = task - l * 192;
    const int kh = r3 >= 96 ? 1 : 0;
    const int grp = r3 - kh * 96;                    // 0..95
    const int tile = grp * 4 + wv;
    const int NSL = l ? 16 : 10;
    const int p = (grp < 24) ? 0 : (grp < 32) ? 1 : (2 + ((grp - 32) >> 3));
    const bool useLo = (p < 2);                      // block-uniform

    const ushort* wf = (const ushort*)(ws + OFF_WF);
    const ushort* fe = (const ushort*)(ws + OFF_FF);
    float* pout = ws + (l ? OFF_P1 : OFF_P0) + (size_t)kh * 393216;

    const int wid = l * 768 + kh * 384 + tile;
    const size_t sbase = l ? (7680 + (size_t)(wid - 768) * 16) : (size_t)wid * 10;
    const size_t fbase = (l ? FLB1 : 0) +
                         ((size_t)(p * 2 + kh) * NSL) * 2048;

    const int m = lane & 15, kg = lane >> 4;
    const int o0 = tile * 16;

    f32x4 acc[4] = {{0,0,0,0},{0,0,0,0},{0,0,0,0},{0,0,0,0}};

    // ---- prologue: slice 0 staged, slice 0 weights in regs ----
    {
        sfh[0][t] = *(const short8v*)(fe + fbase + (size_t)t * 8);
        if (useLo)
            sfl[0][t] = *(const short8v*)(fe + FFLO + fbase + (size_t)t * 8);
    }
    short8v cwh = *(const short8v*)(wf + sbase * 512 + (size_t)lane * 8);
    short8v cwl = cwh;
    if (useLo)
        cwl = *(const short8v*)(wf + WFLO + sbase * 512 + (size_t)lane * 8);
    __syncthreads();

    int cur = 0;
    for (int sl = 0; sl < NSL; ++sl) {
        const bool hasNext = (sl + 1 < NSL);
        short8v nfh, nfl, nwh, nwl;
        if (hasNext) {                               // ISSUE next loads first
            const size_t nb = fbase + (size_t)(sl + 1) * 2048 + (size_t)t * 8;
            nfh = *(const short8v*)(fe + nb);
            if (useLo) nfl = *(const short8v*)(fe + FFLO + nb);
            const size_t wb = (sbase + sl + 1) * 512 + (size_t)lane * 8;
            nwh = *(const short8v*)(wf + wb);
            if (useLo) nwl = *(const short8v*)(wf + WFLO + wb);
        }

        // MFMA cluster (loads in flight above)
        if (useLo) {
#pragma unroll
            for (int bt = 0; bt < 4; ++bt) {
                short8v bh = sfh[cur][bt * 64 + lane];
                short8v bl = sfl[cur][bt * 64 + lane];
                acc[bt] = __builtin_amdgcn_mfma_f32_16x16x32_bf16(cwh, bh, acc[bt], 0, 0, 0);
                acc[bt] = __builtin_amdgcn_mfma_f32_16x16x32_bf16(cwh, bl, acc[bt], 0, 0, 0);
                acc[bt] = __builtin_amdgcn_mfma_f32_16x16x32_bf16(cwl, bh, acc[bt], 0, 0, 0);
            }
        } else {
#pragma unroll
            for (int bt = 0; bt < 4; ++bt) {
                short8v bh = sfh[cur][bt * 64 + lane];
                acc[bt] = __builtin_amdgcn_mfma_f32_16x16x32_bf16(cwh, bh, acc[bt], 0, 0, 0);
            }
        }

        if (hasNext) {                               // WRITE late (other buffer)
            sfh[cur ^ 1][t] = nfh;
            if (useLo) sfl[cur ^ 1][t] = nfl;
            cwh = nwh;
            if (useLo) cwl = nwl;
            __syncthreads();                         // one barrier per slice
            cur ^= 1;
        }
    }

#pragma unroll
    for (int bt = 0; bt < 4; ++bt) {
        float* dst = pout + (size_t)(bt * 16 + m) * 6144 + o0 + kg * 4;
        *(float4*)dst = (float4){acc[bt][0], acc[bt][1], acc[bt][2], acc[bt][3]};
    }
}

// phase B: cell updates (sum 2 K-halves) + feature generation (fragment order).
// Identical to r23.
__global__ __launch_bounds__(256) void phaseB_kernel(
    float* __restrict__ ws,
    const float* __restrict__ b_ih0, const float* __restrict__ b_hh0,
    const float* __restrict__ b_ih1, const float* __restrict__ b_hh1,
    const float* __restrict__ x, int s)
{
    ushort* fe = (ushort*)(ws + OFF_FF);
    float* c0T = ws + OFF_ST;
    float* h1T = c0T + 32768;
    float* c1T = h1T + 32768;
    const float* p0 = ws + OFF_P0;
    const float* p1 = ws + OFF_P1;

    const int u = blockIdx.x * 256 + threadIdx.x;    // 288*256 = 73728
    if (u < 32768) {
        if (s >= TT) return;
        const int o = u & 511, b = u >> 9;
        auto P = [&](int rw) {
            return p0[(size_t)b * 6144 + rw] + p0[393216 + (size_t)b * 6144 + rw];
        };
        float si = P(o)        + b_ih0[o]        + b_hh0[o];
        float sf = P(512 + o)  + b_ih0[512 + o]  + b_hh0[512 + o];
        float sO = P(1024 + o) + b_ih0[1024 + o] + b_hh0[1024 + o];
        float sk = P(1536 + o);
#pragma unroll
        for (int rr = 0; rr < 8; ++rr) sk += P(2048 + rr * 512 + o);
        float ig = sigmoidf_(si), fg = sigmoidf_(sf), og = sigmoidf_(sO);
        float c = fg * c0T[(size_t)b * 512 + o] + ig * sk;
        c0T[(size_t)b * 512 + o] = c;
        float z = og * tanhf(c);
        putFeat(1, o, b, z, fe);                     // L1 input, t=s
        putFeat(0, 128 + o, b, z, fe);               // L0 hidden, t=s+1
    } else if (u < 65536) {
        if (s < 1) return;
        const int v = u - 32768, o = v & 511, b = v >> 9;
        auto P = [&](int rw) {
            return p1[(size_t)b * 6144 + rw] + p1[393216 + (size_t)b * 6144 + rw];
        };
        float si = P(o)        + b_ih1[o]        + b_hh1[o];
        float sf = P(512 + o)  + b_ih1[512 + o]  + b_hh1[512 + o];
        float sO = P(1024 + o) + b_ih1[1024 + o] + b_hh1[1024 + o];
        float sk = P(1536 + o);
#pragma unroll
        for (int rr = 0; rr < 8; ++rr) sk += P(2048 + rr * 512 + o);
        float ig = sigmoidf_(si), fg = sigmoidf_(sf), og = sigmoidf_(sO);
        float c = fg * c1T[(size_t)b * 512 + o] + ig * sk;
        c1T[(size_t)b * 512 + o] = c;
        float z = og * tanhf(c);
        h1T[(size_t)b * 512 + o] = z;
        putFeat(1, 512 + o, b, z, fe);               // L1 hidden, t=s
    } else {
        if (s + 1 >= TT) return;
        const int v = u - 65536, k = v & 127, b = v >> 7;
        putFeat(0, k, b, x[((size_t)b * TT + (s + 1)) * 128 + k], fe);  // L0 x, t=s+1
    }
}

// out[b][jo] = h1T[b] . fc_w[jo] + fc_b[jo]  (fp32 out)
__global__ __launch_bounds__(256) void final_fc(
    const float* __restrict__ h1T, const float* __restrict__ fc_w,
    const float* __restrict__ fc_b, float* __restrict__ out)
{
    const int gid = blockIdx.x * 256 + threadIdx.x;   // 8192
    const int b = gid & 63, jo = gid >> 6;
    float a = fc_b[jo];
    const float* hr = h1T + (size_t)b * 512;
    const float* wr = fc_w + (size_t)jo * 512;
    for (int o = 0; o < 512; o += 4) {
        float4 h4 = *(const float4*)(hr + o);
        float4 w4 = *(const float4*)(wr + o);
        a = fmaf(h4.x, w4.x, a); a = fmaf(h4.y, w4.y, a);
        a = fmaf(h4.z, w4.z, a); a = fmaf(h4.w, w4.w, a);
    }
    out[(size_t)b * 128 + jo] = a;
}

} // namespace

extern "C" void kernel_launch(void* const* d_in, const int* in_sizes, int n_in,
                              void* d_out, int out_size, void* d_ws, size_t ws_size,
                              hipStream_t stream) {
    (void)out_size;
    float* out = (float*)d_out;

    static const int EXP_SIZES[15] = {
        64 * 256 * 128, 1536 * 128, 1536 * 512, 1536, 1536,
        512 * 640, 512 * 640 * 8,
        1536 * 512, 1536 * 512, 1536, 1536,
        512 * 1024, 512 * 1024 * 8,
        128 * 512, 128
    };
    if (n_in != 15) { sentinel_kernel<<<32, 256, 0, stream>>>(out, 111.0f); return; }
    for (int i = 0; i < 15; ++i)
        if (in_sizes[i] != EXP_SIZES[i]) {
            sentinel_kernel<<<32, 256, 0, stream>>>(out, 200.0f * (i + 1)); return;
        }
    if (ws_size < WS_NEED) { sentinel_kernel<<<32, 256, 0, stream>>>(out, 7777.0f); return; }

    const float* x     = (const float*)d_in[0];
    const float* w_ih0 = (const float*)d_in[1];
    const float* w_hh0 = (const float*)d_in[2];
    const float* b_ih0 = (const float*)d_in[3];
    const float* b_hh0 = (const float*)d_in[4];
    const float* kb0   = (const float*)d_in[5];
    const float* ksp0  = (const float*)d_in[6];
    const float* w_ih1 = (const float*)d_in[7];
    const float* w_hh1 = (const float*)d_in[8];
    const float* b_ih1 = (const float*)d_in[9];
    const float* b_hh1 = (const float*)d_in[10];
    const float* kb1   = (const float*)d_in[11];
    const float* ksp1  = (const float*)d_in[12];
    const float* fc_w  = (const float*)d_in[13];
    const float* fc_b  = (const float*)d_in[14];

    float* ws = (float*)d_ws;

    prologue_kernel<<<672, 256, 0, stream>>>(x, ws);
    wbuild_kernel<<<4992, 256, 0, stream>>>((ushort*)(ws + OFF_WF),
        w_ih0, w_hh0, kb0, ksp0, w_ih1, w_hh1, kb1, ksp1);

    for (int s = 0; s <= TT; ++s) {
        phaseA_kernel<<<384, 256, 0, stream>>>(ws, s);
        phaseB_kernel<<<288, 256, 0, stream>>>(
            ws, b_ih0, b_hh0, b_ih1, b_hh1, x, s);
    }

    final_fc<<<32, 256, 0, stream>>>(ws + OFF_ST + 32768, fc_w, fc_b, out);
}

// Round 26
// 4827.198 us; speedup vs baseline: 1.2042x; 1.2042x over previous
//
#include <hip/hip_runtime.h>
#include <math.h>
#include <stdint.h>

namespace {

typedef __attribute__((ext_vector_type(8))) short short8v;   // 8 bf16 = 4 VGPR
typedef __attribute__((ext_vector_type(4))) float f32x4;

constexpr int TT = 256;

// ---- ws float offsets (total 12,959,744 floats = 51.84 MB) ----
constexpr size_t OFF_ST = 0;          // c0T,h1T,c1T [3][64][512]
constexpr size_t OFF_P0 = 98304;      // [2][64][6144]
constexpr size_t OFF_P1 = 884736;     // [2][64][6144]
constexpr size_t OFF_WF = 1671168;    // 20,447,232 ushorts: frag weights hi|lo
constexpr size_t OFF_FF = 11894784;   // 2,129,920 ushorts: frag features hi|lo
constexpr size_t WS_NEED = 12959744ull * 4;

constexpr size_t WFLO = 10223616;     // ushort offset of weight lo plane
constexpr size_t FFLO = 1064960;      // ushort offset of feature lo plane
constexpr size_t FLB1 = 409600;       // feature base of layer 1 (ushorts)

__device__ __forceinline__ float sigmoidf_(float v) { return 1.0f / (1.0f + expf(-v)); }

__device__ __forceinline__ ushort bf16h(float v) {          // RNE f32 -> bf16 bits
    uint32_t u = __float_as_uint(v);
    return (ushort)((u + 0x7fffu + ((u >> 16) & 1u)) >> 16);
}
__device__ __forceinline__ float bf16f(ushort h) { return __uint_as_float(((uint32_t)h) << 16); }

// Cox-de Boor, GRID_SIZE=5, ORDER=3 (verified rounds 7-25)
__device__ __forceinline__ void bspline8(float x, float* out) {
    const float KG[12] = {-2.2f,-1.8f,-1.4f,-1.0f,-0.6f,-0.2f,
                           0.2f, 0.6f, 1.0f, 1.4f, 1.8f, 2.2f};
    float b[11];
#pragma unroll
    for (int i = 0; i < 11; ++i)
        b[i] = (x >= KG[i] && x < KG[i + 1]) ? 1.0f : 0.0f;
#pragma unroll
    for (int p = 1; p <= 3; ++p) {
#pragma unroll
        for (int i = 0; i + p < 11; ++i) {
            float l = (x - KG[i])         * (1.0f / (KG[i + p] - KG[i]));
            float r = (KG[i + p + 1] - x) * (1.0f / (KG[i + p + 1] - KG[i + 1]));
            b[i] = l * b[i] + r * b[i + 1];
        }
    }
#pragma unroll
    for (int i = 0; i < 8; ++i) out[i] = b[i];
}

// Write z, silu, 8 bases for (layer l, feature k, batch b) in FRAGMENT order.
// (r23 version: hi+lo for all planes.)
__device__ __forceinline__ void putFeat(int l, int k, int b, float z,
                                        ushort* __restrict__ fe)
{
    const int NSL = l ? 16 : 10, KC = l ? 512 : 320;
    const int kh = (k >= KC) ? 1 : 0, kr = k - kh * KC;
    const int sl = kr >> 5, kg = (kr >> 3) & 3, j = kr & 7;
    const size_t cell = (size_t)((b >> 4) * 64 + (b & 15) + 16 * kg) * 8 + j;
    const size_t LB = l ? FLB1 : 0;
    const size_t slb = ((size_t)kh * NSL + sl) * 2048 + cell;
    const size_t pstep = (size_t)2 * NSL * 2048;

    auto putp = [&](int p, float v) {
        size_t idx = LB + (size_t)p * pstep + slb;
        ushort h = bf16h(v);
        fe[idx] = h;
        fe[FFLO + idx] = bf16h(v - bf16f(h));
    };
    putp(0, z);
    putp(1, z / (1.0f + expf(-z)));
    float bs[8];
    bspline8(z, bs);
#pragma unroll
    for (int r = 0; r < 8; ++r) putp(2 + r, bs[r]);
}

__global__ __launch_bounds__(256) void sentinel_kernel(float* out, float v) {
    int i = blockIdx.x * 256 + threadIdx.x;
    if (i < 8192) out[i] = v;
}

// Build fragment-ordered split weights (identical to rounds 19-25).
__global__ __launch_bounds__(256) void wbuild_kernel(
    ushort* __restrict__ wf,
    const float* __restrict__ w_ih0, const float* __restrict__ w_hh0,
    const float* __restrict__ kb0, const float* __restrict__ ksp0,
    const float* __restrict__ w_ih1, const float* __restrict__ w_hh1,
    const float* __restrict__ kb1, const float* __restrict__ ksp1)
{
    const int gid = blockIdx.x * 256 + threadIdx.x;   // 4992*256 = 19968*64
    const int s = gid >> 6, lane = gid & 63;
    int wid, sl;
    if (s < 7680) { wid = s / 10; sl = s % 10; }
    else          { wid = 768 + (s - 7680) / 16; sl = (s - 7680) % 16; }
    const int l = wid >= 768 ? 1 : 0;
    const int r2 = wid - l * 768;
    const int kh = r2 >= 384 ? 1 : 0;
    const int tile = r2 - kh * 384;
    const int IN = l ? 512 : 128, W = IN + 512, KC = W >> 1;
    const int m = lane & 15, kg = lane >> 4;
    const int k0 = kh * KC + sl * 32;
    const int kk = k0 + kg * 8;
    const int o0 = tile * 16;

    const float* w_ih = l ? w_ih1 : w_ih0;
    const float* w_hh = l ? w_hh1 : w_hh0;
    const float* kb   = l ? kb1 : kb0;
    const float* ksp  = l ? ksp1 : ksp0;

    float vv[8];
    if (tile < 96) {
        const int row = o0 + m;
#pragma unroll
        for (int j = 0; j < 8; ++j) {
            const int k = kk + j;
            vv[j] = (k0 < IN) ? w_ih[(size_t)row * IN + k]
                              : w_hh[(size_t)row * 512 + (k - IN)];
        }
    } else if (tile < 128) {
        const int row = (tile - 96) * 16 + m;
#pragma unroll
        for (int j = 0; j < 8; ++j) vv[j] = kb[(size_t)row * W + kk + j];
    } else {
        const int rr = (tile - 128) >> 5, op = ((tile - 128) & 31) * 16 + m;
#pragma unroll
        for (int j = 0; j < 8; ++j)
            vv[j] = ksp[((size_t)op * W + kk + j) * 8 + rr];
    }
    const size_t base = (size_t)s * 512 + (size_t)lane * 8;
#pragma unroll
    for (int j = 0; j < 8; ++j) {
        ushort h = bf16h(vv[j]);
        wf[base + j] = h;
        wf[WFLO + base + j] = bf16h(vv[j] - bf16f(h));
    }
}

// states zero + t=0 x-features + zero-state hidden features for both layers
__global__ __launch_bounds__(256) void prologue_kernel(
    const float* __restrict__ x, float* __restrict__ ws)
{
    ushort* fe = (ushort*)(ws + OFF_FF);
    const int g = blockIdx.x * 256 + threadIdx.x;    // 672*256 = 172032
    if (g < 98304) {
        ws[OFF_ST + g] = 0.0f;                       // c0T,h1T,c1T
    } else if (g < 106496) {                         // t=0 x feats (k<128)
        const int i = g - 98304, k = i & 127, b = i >> 7;
        putFeat(0, k, b, x[((size_t)b * TT) * 128 + k], fe);
    } else if (g < 139264) {                         // L0 hidden feats h0(-1)=0
        const int i = g - 106496, o = i & 511, b = i >> 9;
        putFeat(0, 128 + o, b, 0.0f, fe);
    } else {                                         // L1 hidden feats h1(-1)=0
        const int i = g - 139264, o = i & 511, b = i >> 9;
        putFeat(1, 512 + o, b, 0.0f, fe);
    }
}

// phase A: MFMA GEMM, split-bf16 (3 products), fragment-ordered memory,
// XCD swizzle, double-buffered LDS — r23 base. ONE change: DEPTH-2 prefetch.
// At iter sl: issue slice sl+2 loads into regsB; MFMA slice sl; write slice
// sl+1 (regsA, loaded a full iteration ago -> latency covered) to LDS;
// barrier; shift B->A. Same MFMA order -> bit-identical numerics.
__global__ __launch_bounds__(256) void phaseA_kernel(
    float* __restrict__ ws, int s)
{
    __shared__ short8v sfh[2][256], sfl[2][256];     // 16 KB

    const int t = threadIdx.x, lane = t & 63;
    const int wv = __builtin_amdgcn_readfirstlane(t >> 6);
    const int bid = blockIdx.x;                      // 0..383
    const int task = ((bid & 7) * 48) + (bid >> 3);  // XCD-contiguous tasks
    const int l  = task >= 192 ? 1 : 0;
    if (l ? (s < 1) : (s >= TT)) return;             // block-uniform
    const int r3 = task - l * 192;
    const int kh = r3 >= 96 ? 1 : 0;
    const int grp = r3 - kh * 96;                    // 0..95
    const int tile = grp * 4 + wv;
    const int NSL = l ? 16 : 10;
    const int p = (grp < 24) ? 0 : (grp < 32) ? 1 : (2 + ((grp - 32) >> 3));

    const ushort* wf = (const ushort*)(ws + OFF_WF);
    const ushort* fe = (const ushort*)(ws + OFF_FF);
    float* pout = ws + (l ? OFF_P1 : OFF_P0) + (size_t)kh * 393216;

    const int wid = l * 768 + kh * 384 + tile;
    const size_t sbase = l ? (7680 + (size_t)(wid - 768) * 16) : (size_t)wid * 10;
    const size_t fbase = (l ? FLB1 : 0) +
                         ((size_t)(p * 2 + kh) * NSL) * 2048;

    const int m = lane & 15, kg = lane >> 4;
    const int o0 = tile * 16;

    f32x4 acc[4] = {{0,0,0,0},{0,0,0,0},{0,0,0,0},{0,0,0,0}};

    // ---- prologue: slice 0 -> LDS; slice 1 -> regsA; slice-0 weights ----
    sfh[0][t] = *(const short8v*)(fe + fbase + (size_t)t * 8);
    sfl[0][t] = *(const short8v*)(fe + FFLO + fbase + (size_t)t * 8);
    short8v cwh = *(const short8v*)(wf + sbase * 512 + (size_t)lane * 8);
    short8v cwl = *(const short8v*)(wf + WFLO + sbase * 512 + (size_t)lane * 8);
    short8v afh, afl, awh, awl;
    {
        const size_t nb = fbase + 2048 + (size_t)t * 8;
        afh = *(const short8v*)(fe + nb);
        afl = *(const short8v*)(fe + FFLO + nb);
        const size_t wb = (sbase + 1) * 512 + (size_t)lane * 8;
        awh = *(const short8v*)(wf + wb);
        awl = *(const short8v*)(wf + WFLO + wb);
    }
    __syncthreads();

    int cur = 0;
    for (int sl = 0; sl < NSL; ++sl) {
        short8v bfh, bfl, bwh, bwl;
        const bool has2 = (sl + 2 < NSL);
        if (has2) {                                  // issue slice sl+2 loads
            const size_t nb = fbase + (size_t)(sl + 2) * 2048 + (size_t)t * 8;
            bfh = *(const short8v*)(fe + nb);
            bfl = *(const short8v*)(fe + FFLO + nb);
            const size_t wb = (sbase + sl + 2) * 512 + (size_t)lane * 8;
            bwh = *(const short8v*)(wf + wb);
            bwl = *(const short8v*)(wf + WFLO + wb);
        }

        // MFMA cluster on slice sl
#pragma unroll
        for (int bt = 0; bt < 4; ++bt) {
            short8v bh = sfh[cur][bt * 64 + lane];
            short8v bl = sfl[cur][bt * 64 + lane];
            acc[bt] = __builtin_amdgcn_mfma_f32_16x16x32_bf16(cwh, bh, acc[bt], 0, 0, 0);
            acc[bt] = __builtin_amdgcn_mfma_f32_16x16x32_bf16(cwh, bl, acc[bt], 0, 0, 0);
            acc[bt] = __builtin_amdgcn_mfma_f32_16x16x32_bf16(cwl, bh, acc[bt], 0, 0, 0);
        }

        if (sl + 1 < NSL) {                          // write slice sl+1 (regsA)
            sfh[cur ^ 1][t] = afh;
            sfl[cur ^ 1][t] = afl;
            cwh = awh; cwl = awl;
            __syncthreads();                         // one barrier per slice
            cur ^= 1;
            afh = bfh; afl = bfl; awh = bwh; awl = bwl;   // shift B -> A
        }
    }

#pragma unroll
    for (int bt = 0; bt < 4; ++bt) {
        float* dst = pout + (size_t)(bt * 16 + m) * 6144 + o0 + kg * 4;
        *(float4*)dst = (float4){acc[bt][0], acc[bt][1], acc[bt][2], acc[bt][3]};
    }
}

// phase B: cell updates (sum 2 K-halves) + feature generation (fragment order).
// Identical to r23 (288 blocks, direct mapping).
__global__ __launch_bounds__(256) void phaseB_kernel(
    float* __restrict__ ws,
    const float* __restrict__ b_ih0, const float* __restrict__ b_hh0,
    const float* __restrict__ b_ih1, const float* __restrict__ b_hh1,
    const float* __restrict__ x, int s)
{
    ushort* fe = (ushort*)(ws + OFF_FF);
    float* c0T = ws + OFF_ST;
    float* h1T = c0T + 32768;
    float* c1T = h1T + 32768;
    const float* p0 = ws + OFF_P0;
    const float* p1 = ws + OFF_P1;

    const int u = blockIdx.x * 256 + threadIdx.x;    // 288*256 = 73728
    if (u < 32768) {
        if (s >= TT) return;
        const int o = u & 511, b = u >> 9;
        auto P = [&](int rw) {
            return p0[(size_t)b * 6144 + rw] + p0[393216 + (size_t)b * 6144 + rw];
        };
        float si = P(o)        + b_ih0[o]        + b_hh0[o];
        float sf = P(512 + o)  + b_ih0[512 + o]  + b_hh0[512 + o];
        float sO = P(1024 + o) + b_ih0[1024 + o] + b_hh0[1024 + o];
        float sk = P(1536 + o);
#pragma unroll
        for (int rr = 0; rr < 8; ++rr) sk += P(2048 + rr * 512 + o);
        float ig = sigmoidf_(si), fg = sigmoidf_(sf), og = sigmoidf_(sO);
        float c = fg * c0T[(size_t)b * 512 + o] + ig * sk;
        c0T[(size_t)b * 512 + o] = c;
        float z = og * tanhf(c);
        putFeat(1, o, b, z, fe);                     // L1 input, t=s
        putFeat(0, 128 + o, b, z, fe);               // L0 hidden, t=s+1
    } else if (u < 65536) {
        if (s < 1) return;
        const int v = u - 32768, o = v & 511, b = v >> 9;
        auto P = [&](int rw) {
            return p1[(size_t)b * 6144 + rw] + p1[393216 + (size_t)b * 6144 + rw];
        };
        float si = P(o)        + b_ih1[o]        + b_hh1[o];
        float sf = P(512 + o)  + b_ih1[512 + o]  + b_hh1[512 + o];
        float sO = P(1024 + o) + b_ih1[1024 + o] + b_hh1[1024 + o];
        float sk = P(1536 + o);
#pragma unroll
        for (int rr = 0; rr < 8; ++rr) sk += P(2048 + rr * 512 + o);
        float ig = sigmoidf_(si), fg = sigmoidf_(sf), og = sigmoidf_(sO);
        float c = fg * c1T[(size_t)b * 512 + o] + ig * sk;
        c1T[(size_t)b * 512 + o] = c;
        float z = og * tanhf(c);
        h1T[(size_t)b * 512 + o] = z;
        putFeat(1, 512 + o, b, z, fe);               // L1 hidden, t=s
    } else {
        if (s + 1 >= TT) return;
        const int v = u - 65536, k = v & 127, b = v >> 7;
        putFeat(0, k, b, x[((size_t)b * TT + (s + 1)) * 128 + k], fe);  // L0 x, t=s+1
    }
}

// out[b][jo] = h1T[b] . fc_w[jo] + fc_b[jo]  (fp32 out)
__global__ __launch_bounds__(256) void final_fc(
    const float* __restrict__ h1T, const float* __restrict__ fc_w,
    const float* __restrict__ fc_b, float* __restrict__ out)
{
    const int gid = blockIdx.x * 256 + threadIdx.x;   // 8192
    const int b = gid & 63, jo = gid >> 6;
    float a = fc_b[jo];
    const float* hr = h1T + (size_t)b * 512;
    const float* wr = fc_w + (size_t)jo * 512;
    for (int o = 0; o < 512; o += 4) {
        float4 h4 = *(const float4*)(hr + o);
        float4 w4 = *(const float4*)(wr + o);
        a = fmaf(h4.x, w4.x, a); a = fmaf(h4.y, w4.y, a);
        a = fmaf(h4.z, w4.z, a); a = fmaf(h4.w, w4.w, a);
    }
    out[(size_t)b * 128 + jo] = a;
}

} // namespace

extern "C" void kernel_launch(void* const* d_in, const int* in_sizes, int n_in,
                              void* d_out, int out_size, void* d_ws, size_t ws_size,
                              hipStream_t stream) {
    (void)out_size;
    float* out = (float*)d_out;

    static const int EXP_SIZES[15] = {
        64 * 256 * 128, 1536 * 128, 1536 * 512, 1536, 1536,
        512 * 640, 512 * 640 * 8,
        1536 * 512, 1536 * 512, 1536, 1536,
        512 * 1024, 512 * 1024 * 8,
        128 * 512, 128
    };
    if (n_in != 15) { sentinel_kernel<<<32, 256, 0, stream>>>(out, 111.0f); return; }
    for (int i = 0; i < 15; ++i)
        if (in_sizes[i] != EXP_SIZES[i]) {
            sentinel_kernel<<<32, 256, 0, stream>>>(out, 200.0f * (i + 1)); return;
        }
    if (ws_size < WS_NEED) { sentinel_kernel<<<32, 256, 0, stream>>>(out, 7777.0f); return; }

    const float* x     = (const float*)d_in[0];
    const float* w_ih0 = (const float*)d_in[1];
    const float* w_hh0 = (const float*)d_in[2];
    const float* b_ih0 = (const float*)d_in[3];
    const float* b_hh0 = (const float*)d_in[4];
    const float* kb0   = (const float*)d_in[5];
    const float* ksp0  = (const float*)d_in[6];
    const float* w_ih1 = (const float*)d_in[7];
    const float* w_hh1 = (const float*)d_in[8];
    const float* b_ih1 = (const float*)d_in[9];
    const float* b_hh1 = (const float*)d_in[10];
    const float* kb1   = (const float*)d_in[11];
    const float* ksp1  = (const float*)d_in[12];
    const float* fc_w  = (const float*)d_in[13];
    const float* fc_b  = (const float*)d_in[14];

    float* ws = (float*)d_ws;

    prologue_kernel<<<672, 256, 0, stream>>>(x, ws);
    wbuild_kernel<<<4992, 256, 0, stream>>>((ushort*)(ws + OFF_WF),
        w_ih0, w_hh0, kb0, ksp0, w_ih1, w_hh1, kb1, ksp1);

    for (int s = 0; s <= TT; ++s) {
        phaseA_kernel<<<384, 256, 0, stream>>>(ws, s);
        phaseB_kernel<<<288, 256, 0, stream>>>(
            ws, b_ih0, b_hh0, b_ih1, b_hh1, x, s);
    }

    final_fc<<<32, 256, 0, stream>>>(ws + OFF_ST + 32768, fc_w, fc_b, out);
}

// Round 27
// 4750.491 us; speedup vs baseline: 1.2236x; 1.0161x over previous
//
#include <hip/hip_runtime.h>
#include <math.h>
#include <stdint.h>

namespace {

typedef __attribute__((ext_vector_type(8))) short short8v;   // 8 bf16 = 4 VGPR
typedef __attribute__((ext_vector_type(4))) float f32x4;

constexpr int TT = 256;

// ---- ws float offsets (total 12,959,744 floats = 51.84 MB) ----
constexpr size_t OFF_ST = 0;          // c0T,h1T,c1T [3][64][512]
constexpr size_t OFF_P0 = 98304;      // [2][64][6144]
constexpr size_t OFF_P1 = 884736;     // [2][64][6144]
constexpr size_t OFF_WF = 1671168;    // 20,447,232 ushorts: frag weights hi|lo
constexpr size_t OFF_FF = 11894784;   // 2,129,920 ushorts: frag features hi|lo
constexpr size_t WS_NEED = 12959744ull * 4;

constexpr size_t WFLO = 10223616;     // ushort offset of weight lo plane
constexpr size_t FFLO = 1064960;      // ushort offset of feature lo plane
constexpr size_t FLB1 = 409600;       // feature base of layer 1 (ushorts)

__device__ __forceinline__ float sigmoidf_(float v) { return 1.0f / (1.0f + expf(-v)); }

__device__ __forceinline__ ushort bf16h(float v) {          // RNE f32 -> bf16 bits
    uint32_t u = __float_as_uint(v);
    return (ushort)((u + 0x7fffu + ((u >> 16) & 1u)) >> 16);
}
__device__ __forceinline__ float bf16f(ushort h) { return __uint_as_float(((uint32_t)h) << 16); }

// Cox-de Boor, GRID_SIZE=5, ORDER=3 (verified rounds 7-26)
__device__ __forceinline__ void bspline8(float x, float* out) {
    const float KG[12] = {-2.2f,-1.8f,-1.4f,-1.0f,-0.6f,-0.2f,
                           0.2f, 0.6f, 1.0f, 1.4f, 1.8f, 2.2f};
    float b[11];
#pragma unroll
    for (int i = 0; i < 11; ++i)
        b[i] = (x >= KG[i] && x < KG[i + 1]) ? 1.0f : 0.0f;
#pragma unroll
    for (int p = 1; p <= 3; ++p) {
#pragma unroll
        for (int i = 0; i + p < 11; ++i) {
            float l = (x - KG[i])         * (1.0f / (KG[i + p] - KG[i]));
            float r = (KG[i + p + 1] - x) * (1.0f / (KG[i + p + 1] - KG[i + 1]));
            b[i] = l * b[i] + r * b[i + 1];
        }
    }
#pragma unroll
    for (int i = 0; i < 8; ++i) out[i] = b[i];
}

// Write z, silu, 8 bases for (layer l, feature k, batch b) in FRAGMENT order.
__device__ __forceinline__ void putFeat(int l, int k, int b, float z,
                                        ushort* __restrict__ fe)
{
    const int NSL = l ? 16 : 10, KC = l ? 512 : 320;
    const int kh = (k >= KC) ? 1 : 0, kr = k - kh * KC;
    const int sl = kr >> 5, kg = (kr >> 3) & 3, j = kr & 7;
    const size_t cell = (size_t)((b >> 4) * 64 + (b & 15) + 16 * kg) * 8 + j;
    const size_t LB = l ? FLB1 : 0;
    const size_t slb = ((size_t)kh * NSL + sl) * 2048 + cell;
    const size_t pstep = (size_t)2 * NSL * 2048;

    auto putp = [&](int p, float v) {
        size_t idx = LB + (size_t)p * pstep + slb;
        ushort h = bf16h(v);
        fe[idx] = h;
        fe[FFLO + idx] = bf16h(v - bf16f(h));
    };
    putp(0, z);
    putp(1, z / (1.0f + expf(-z)));
    float bs[8];
    bspline8(z, bs);
#pragma unroll
    for (int r = 0; r < 8; ++r) putp(2 + r, bs[r]);
}

__global__ __launch_bounds__(256) void sentinel_kernel(float* out, float v) {
    int i = blockIdx.x * 256 + threadIdx.x;
    if (i < 8192) out[i] = v;
}

// Build fragment-ordered split weights (identical to rounds 19-26).
__global__ __launch_bounds__(256) void wbuild_kernel(
    ushort* __restrict__ wf,
    const float* __restrict__ w_ih0, const float* __restrict__ w_hh0,
    const float* __restrict__ kb0, const float* __restrict__ ksp0,
    const float* __restrict__ w_ih1, const float* __restrict__ w_hh1,
    const float* __restrict__ kb1, const float* __restrict__ ksp1)
{
    const int gid = blockIdx.x * 256 + threadIdx.x;   // 4992*256 = 19968*64
    const int s = gid >> 6, lane = gid & 63;
    int wid, sl;
    if (s < 7680) { wid = s / 10; sl = s % 10; }
    else          { wid = 768 + (s - 7680) / 16; sl = (s - 7680) % 16; }
    const int l = wid >= 768 ? 1 : 0;
    const int r2 = wid - l * 768;
    const int kh = r2 >= 384 ? 1 : 0;
    const int tile = r2 - kh * 384;
    const int IN = l ? 512 : 128, W = IN + 512, KC = W >> 1;
    const int m = lane & 15, kg = lane >> 4;
    const int k0 = kh * KC + sl * 32;
    const int kk = k0 + kg * 8;
    const int o0 = tile * 16;

    const float* w_ih = l ? w_ih1 : w_ih0;
    const float* w_hh = l ? w_hh1 : w_hh0;
    const float* kb   = l ? kb1 : kb0;
    const float* ksp  = l ? ksp1 : ksp0;

    float vv[8];
    if (tile < 96) {
        const int row = o0 + m;
#pragma unroll
        for (int j = 0; j < 8; ++j) {
            const int k = kk + j;
            vv[j] = (k0 < IN) ? w_ih[(size_t)row * IN + k]
                              : w_hh[(size_t)row * 512 + (k - IN)];
        }
    } else if (tile < 128) {
        const int row = (tile - 96) * 16 + m;
#pragma unroll
        for (int j = 0; j < 8; ++j) vv[j] = kb[(size_t)row * W + kk + j];
    } else {
        const int rr = (tile - 128) >> 5, op = ((tile - 128) & 31) * 16 + m;
#pragma unroll
        for (int j = 0; j < 8; ++j)
            vv[j] = ksp[((size_t)op * W + kk + j) * 8 + rr];
    }
    const size_t base = (size_t)s * 512 + (size_t)lane * 8;
#pragma unroll
    for (int j = 0; j < 8; ++j) {
        ushort h = bf16h(vv[j]);
        wf[base + j] = h;
        wf[WFLO + base + j] = bf16h(vv[j] - bf16f(h));
    }
}

// states zero + t=0 x-features + zero-state hidden features for both layers
__global__ __launch_bounds__(256) void prologue_kernel(
    const float* __restrict__ x, float* __restrict__ ws)
{
    ushort* fe = (ushort*)(ws + OFF_FF);
    const int g = blockIdx.x * 256 + threadIdx.x;    // 672*256 = 172032
    if (g < 98304) {
        ws[OFF_ST + g] = 0.0f;                       // c0T,h1T,c1T
    } else if (g < 106496) {                         // t=0 x feats (k<128)
        const int i = g - 98304, k = i & 127, b = i >> 7;
        putFeat(0, k, b, x[((size_t)b * TT) * 128 + k], fe);
    } else if (g < 139264) {                         // L0 hidden feats h0(-1)=0
        const int i = g - 106496, o = i & 511, b = i >> 9;
        putFeat(0, 128 + o, b, 0.0f, fe);
    } else {                                         // L1 hidden feats h1(-1)=0
        const int i = g - 139264, o = i & 511, b = i >> 9;
        putFeat(1, 512 + o, b, 0.0f, fe);
    }
}

// phase A: MFMA GEMM, split-bf16 (3 products), fragment-ordered memory,
// XCD swizzle, depth-2 register prefetch (all r26). ONE change: LDS buffers
// hold a PAIR of slices -> 24 MFMAs per barrier instead of 12; barriers per
// task halve (16->8 / 10->5). Same MFMA order -> bit-identical numerics.
__global__ __launch_bounds__(256) void phaseA_kernel(
    float* __restrict__ ws, int s)
{
    __shared__ short8v sfh[2][2][256], sfl[2][2][256];   // 32 KB

    const int t = threadIdx.x, lane = t & 63;
    const int wv = __builtin_amdgcn_readfirstlane(t >> 6);
    const int bid = blockIdx.x;                      // 0..383
    const int task = ((bid & 7) * 48) + (bid >> 3);  // XCD-contiguous tasks
    const int l  = task >= 192 ? 1 : 0;
    if (l ? (s < 1) : (s >= TT)) return;             // block-uniform
    const int r3 = task - l * 192;
    const int kh = r3 >= 96 ? 1 : 0;
    const int grp = r3 - kh * 96;                    // 0..95
    const int tile = grp * 4 + wv;
    const int NSL = l ? 16 : 10;
    const int NP  = NSL >> 1;                        // slice pairs (5 or 8)
    const int p = (grp < 24) ? 0 : (grp < 32) ? 1 : (2 + ((grp - 32) >> 3));

    const ushort* wf = (const ushort*)(ws + OFF_WF);
    const ushort* fe = (const ushort*)(ws + OFF_FF);
    float* pout = ws + (l ? OFF_P1 : OFF_P0) + (size_t)kh * 393216;

    const int wid = l * 768 + kh * 384 + tile;
    const size_t sbase = l ? (7680 + (size_t)(wid - 768) * 16) : (size_t)wid * 10;
    const size_t fbase = (l ? FLB1 : 0) +
                         ((size_t)(p * 2 + kh) * NSL) * 2048;

    const int m = lane & 15, kg = lane >> 4;
    const int o0 = tile * 16;

    f32x4 acc[4] = {{0,0,0,0},{0,0,0,0},{0,0,0,0},{0,0,0,0}};

    // ---- prologue: pair 0 -> LDS[0]; pair 1 -> regsA; pair-0 weights ----
    sfh[0][0][t] = *(const short8v*)(fe + fbase + (size_t)t * 8);
    sfl[0][0][t] = *(const short8v*)(fe + FFLO + fbase + (size_t)t * 8);
    sfh[0][1][t] = *(const short8v*)(fe + fbase + 2048 + (size_t)t * 8);
    sfl[0][1][t] = *(const short8v*)(fe + FFLO + fbase + 2048 + (size_t)t * 8);
    short8v cwh0 = *(const short8v*)(wf + (sbase + 0) * 512 + (size_t)lane * 8);
    short8v cwl0 = *(const short8v*)(wf + WFLO + (sbase + 0) * 512 + (size_t)lane * 8);
    short8v cwh1 = *(const short8v*)(wf + (sbase + 1) * 512 + (size_t)lane * 8);
    short8v cwl1 = *(const short8v*)(wf + WFLO + (sbase + 1) * 512 + (size_t)lane * 8);

    short8v af0h, af0l, af1h, af1l, aw0h, aw0l, aw1h, aw1l;
    if (NP > 1) {
        const size_t nb = fbase + 2 * 2048 + (size_t)t * 8;
        af0h = *(const short8v*)(fe + nb);
        af0l = *(const short8v*)(fe + FFLO + nb);
        af1h = *(const short8v*)(fe + nb + 2048);
        af1l = *(const short8v*)(fe + FFLO + nb + 2048);
        const size_t wb = (sbase + 2) * 512 + (size_t)lane * 8;
        aw0h = *(const short8v*)(wf + wb);
        aw0l = *(const short8v*)(wf + WFLO + wb);
        aw1h = *(const short8v*)(wf + wb + 512);
        aw1l = *(const short8v*)(wf + WFLO + wb + 512);
    }
    __syncthreads();

    int cur = 0;
    for (int sp = 0; sp < NP; ++sp) {
        short8v bf0h, bf0l, bf1h, bf1l, bw0h, bw0l, bw1h, bw1l;
        if (sp + 2 < NP) {                           // issue pair sp+2 loads
            const size_t nb = fbase + (size_t)(sp + 2) * 2 * 2048 + (size_t)t * 8;
            bf0h = *(const short8v*)(fe + nb);
            bf0l = *(const short8v*)(fe + FFLO + nb);
            bf1h = *(const short8v*)(fe + nb + 2048);
            bf1l = *(const short8v*)(fe + FFLO + nb + 2048);
            const size_t wb = (sbase + (sp + 2) * 2) * 512 + (size_t)lane * 8;
            bw0h = *(const short8v*)(wf + wb);
            bw0l = *(const short8v*)(wf + WFLO + wb);
            bw1h = *(const short8v*)(wf + wb + 512);
            bw1l = *(const short8v*)(wf + WFLO + wb + 512);
        }

        // MFMA cluster: slice 2sp then 2sp+1 (24 MFMAs per barrier)
#pragma unroll
        for (int bt = 0; bt < 4; ++bt) {
            short8v bh = sfh[cur][0][bt * 64 + lane];
            short8v bl = sfl[cur][0][bt * 64 + lane];
            acc[bt] = __builtin_amdgcn_mfma_f32_16x16x32_bf16(cwh0, bh, acc[bt], 0, 0, 0);
            acc[bt] = __builtin_amdgcn_mfma_f32_16x16x32_bf16(cwh0, bl, acc[bt], 0, 0, 0);
            acc[bt] = __builtin_amdgcn_mfma_f32_16x16x32_bf16(cwl0, bh, acc[bt], 0, 0, 0);
        }
#pragma unroll
        for (int bt = 0; bt < 4; ++bt) {
            short8v bh = sfh[cur][1][bt * 64 + lane];
            short8v bl = sfl[cur][1][bt * 64 + lane];
            acc[bt] = __builtin_amdgcn_mfma_f32_16x16x32_bf16(cwh1, bh, acc[bt], 0, 0, 0);
            acc[bt] = __builtin_amdgcn_mfma_f32_16x16x32_bf16(cwh1, bl, acc[bt], 0, 0, 0);
            acc[bt] = __builtin_amdgcn_mfma_f32_16x16x32_bf16(cwl1, bh, acc[bt], 0, 0, 0);
        }

        if (sp + 1 < NP) {                           // write pair sp+1 (regsA)
            sfh[cur ^ 1][0][t] = af0h;
            sfl[cur ^ 1][0][t] = af0l;
            sfh[cur ^ 1][1][t] = af1h;
            sfl[cur ^ 1][1][t] = af1l;
            cwh0 = aw0h; cwl0 = aw0l; cwh1 = aw1h; cwl1 = aw1l;
            __syncthreads();                         // one barrier per PAIR
            cur ^= 1;
            af0h = bf0h; af0l = bf0l; af1h = bf1h; af1l = bf1l;
            aw0h = bw0h; aw0l = bw0l; aw1h = bw1h; aw1l = bw1l;
        }
    }

#pragma unroll
    for (int bt = 0; bt < 4; ++bt) {
        float* dst = pout + (size_t)(bt * 16 + m) * 6144 + o0 + kg * 4;
        *(float4*)dst = (float4){acc[bt][0], acc[bt][1], acc[bt][2], acc[bt][3]};
    }
}

// phase B: cell updates (sum 2 K-halves) + feature generation (fragment order).
// Identical to r23/r26 (288 blocks, direct mapping).
__global__ __launch_bounds__(256) void phaseB_kernel(
    float* __restrict__ ws,
    const float* __restrict__ b_ih0, const float* __restrict__ b_hh0,
    const float* __restrict__ b_ih1, const float* __restrict__ b_hh1,
    const float* __restrict__ x, int s)
{
    ushort* fe = (ushort*)(ws + OFF_FF);
    float* c0T = ws + OFF_ST;
    float* h1T = c0T + 32768;
    float* c1T = h1T + 32768;
    const float* p0 = ws + OFF_P0;
    const float* p1 = ws + OFF_P1;

    const int u = blockIdx.x * 256 + threadIdx.x;    // 288*256 = 73728
    if (u < 32768) {
        if (s >= TT) return;
        const int o = u & 511, b = u >> 9;
        auto P = [&](int rw) {
            return p0[(size_t)b * 6144 + rw] + p0[393216 + (size_t)b * 6144 + rw];
        };
        float si = P(o)        + b_ih0[o]        + b_hh0[o];
        float sf = P(512 + o)  + b_ih0[512 + o]  + b_hh0[512 + o];
        float sO = P(1024 + o) + b_ih0[1024 + o] + b_hh0[1024 + o];
        float sk = P(1536 + o);
#pragma unroll
        for (int rr = 0; rr < 8; ++rr) sk += P(2048 + rr * 512 + o);
        float ig = sigmoidf_(si), fg = sigmoidf_(sf), og = sigmoidf_(sO);
        float c = fg * c0T[(size_t)b * 512 + o] + ig * sk;
        c0T[(size_t)b * 512 + o] = c;
        float z = og * tanhf(c);
        putFeat(1, o, b, z, fe);                     // L1 input, t=s
        putFeat(0, 128 + o, b, z, fe);               // L0 hidden, t=s+1
    } else if (u < 65536) {
        if (s < 1) return;
        const int v = u - 32768, o = v & 511, b = v >> 9;
        auto P = [&](int rw) {
            return p1[(size_t)b * 6144 + rw] + p1[393216 + (size_t)b * 6144 + rw];
        };
        float si = P(o)        + b_ih1[o]        + b_hh1[o];
        float sf = P(512 + o)  + b_ih1[512 + o]  + b_hh1[512 + o];
        float sO = P(1024 + o) + b_ih1[1024 + o] + b_hh1[1024 + o];
        float sk = P(1536 + o);
#pragma unroll
        for (int rr = 0; rr < 8; ++rr) sk += P(2048 + rr * 512 + o);
        float ig = sigmoidf_(si), fg = sigmoidf_(sf), og = sigmoidf_(sO);
        float c = fg * c1T[(size_t)b * 512 + o] + ig * sk;
        c1T[(size_t)b * 512 + o] = c;
        float z = og * tanhf(c);
        h1T[(size_t)b * 512 + o] = z;
        putFeat(1, 512 + o, b, z, fe);               // L1 hidden, t=s
    } else {
        if (s + 1 >= TT) return;
        const int v = u - 65536, k = v & 127, b = v >> 7;
        putFeat(0, k, b, x[((size_t)b * TT + (s + 1)) * 128 + k], fe);  // L0 x, t=s+1
    }
}

// out[b][jo] = h1T[b] . fc_w[jo] + fc_b[jo]  (fp32 out)
__global__ __launch_bounds__(256) void final_fc(
    const float* __restrict__ h1T, const float* __restrict__ fc_w,
    const float* __restrict__ fc_b, float* __restrict__ out)
{
    const int gid = blockIdx.x * 256 + threadIdx.x;   // 8192
    const int b = gid & 63, jo = gid >> 6;
    float a = fc_b[jo];
    const float* hr = h1T + (size_t)b * 512;
    const float* wr = fc_w + (size_t)jo * 512;
    for (int o = 0; o < 512; o += 4) {
        float4 h4 = *(const float4*)(hr + o);
        float4 w4 = *(const float4*)(wr + o);
        a = fmaf(h4.x, w4.x, a); a = fmaf(h4.y, w4.y, a);
        a = fmaf(h4.z, w4.z, a); a = fmaf(h4.w, w4.w, a);
    }
    out[(size_t)b * 128 + jo] = a;
}

} // namespace

extern "C" void kernel_launch(void* const* d_in, const int* in_sizes, int n_in,
                              void* d_out, int out_size, void* d_ws, size_t ws_size,
                              hipStream_t stream) {
    (void)out_size;
    float* out = (float*)d_out;

    static const int EXP_SIZES[15] = {
        64 * 256 * 128, 1536 * 128, 1536 * 512, 1536, 1536,
        512 * 640, 512 * 640 * 8,
        1536 * 512, 1536 * 512, 1536, 1536,
        512 * 1024, 512 * 1024 * 8,
        128 * 512, 128
    };
    if (n_in != 15) { sentinel_kernel<<<32, 256, 0, stream>>>(out, 111.0f); return; }
    for (int i = 0; i < 15; ++i)
        if (in_sizes[i] != EXP_SIZES[i]) {
            sentinel_kernel<<<32, 256, 0, stream>>>(out, 200.0f * (i + 1)); return;
        }
    if (ws_size < WS_NEED) { sentinel_kernel<<<32, 256, 0, stream>>>(out, 7777.0f); return; }

    const float* x     = (const float*)d_in[0];
    const float* w_ih0 = (const float*)d_in[1];
    const float* w_hh0 = (const float*)d_in[2];
    const float* b_ih0 = (const float*)d_in[3];
    const float* b_hh0 = (const float*)d_in[4];
    const float* kb0   = (const float*)d_in[5];
    const float* ksp0  = (const float*)d_in[6];
    const float* w_ih1 = (const float*)d_in[7];
    const float* w_hh1 = (const float*)d_in[8];
    const float* b_ih1 = (const float*)d_in[9];
    const float* b_hh1 = (const float*)d_in[10];
    const float* kb1   = (const float*)d_in[11];
    const float* ksp1  = (const float*)d_in[12];
    const float* fc_w  = (const float*)d_in[13];
    const float* fc_b  = (const float*)d_in[14];

    float* ws = (float*)d_ws;

    prologue_kernel<<<672, 256, 0, stream>>>(x, ws);
    wbuild_kernel<<<4992, 256, 0, stream>>>((ushort*)(ws + OFF_WF),
        w_ih0, w_hh0, kb0, ksp0, w_ih1, w_hh1, kb1, ksp1);

    for (int s = 0; s <= TT; ++s) {
        phaseA_kernel<<<384, 256, 0, stream>>>(ws, s);
        phaseB_kernel<<<288, 256, 0, stream>>>(
            ws, b_ih0, b_hh0, b_ih1, b_hh1, x, s);
    }

    final_fc<<<32, 256, 0, stream>>>(ws + OFF_ST + 32768, fc_w, fc_b, out);
}